// Round 1
// baseline (3937.731 us; speedup 1.0000x reference)
//
#include <hip/hip_runtime.h>
#include <hip/hip_bf16.h>

#define E_EDGES 1600000
#define NN 100000
#define HID 128

// ---------------------------------------------------------------------------
// Phase 1: gated = (rbf @ W_rbf.T) * x, scatter-add into h[node]
// 32 lanes per edge, each lane owns one float4 (4 dims) of the 128-dim row.
// ---------------------------------------------------------------------------
__global__ __launch_bounds__(256) void edge_gate_scatter(
    const float* __restrict__ x, const float* __restrict__ rbf,
    const int* __restrict__ idx, const float* __restrict__ W_rbf,
    float* __restrict__ h) {
  __shared__ float sW[HID * 6];  // 3 KB
  for (int t = threadIdx.x; t < HID * 6; t += 256) sW[t] = W_rbf[t];
  __syncthreads();

  long long gid = (long long)blockIdx.x * 256 + threadIdx.x;
  long long e = gid >> 5;
  int c = (int)(gid & 31);
  if (e >= E_EDGES) return;

  const float* rb = rbf + e * 6;
  float r0 = rb[0], r1 = rb[1], r2 = rb[2], r3 = rb[3], r4 = rb[4], r5 = rb[5];
  float4 xv = ((const float4*)x)[e * 32 + c];
  int node = idx[e];
  float* hp = h + (long long)node * HID + c * 4;
  float xs[4] = {xv.x, xv.y, xv.z, xv.w};
#pragma unroll
  for (int j = 0; j < 4; ++j) {
    const float* w = &sW[(c * 4 + j) * 6];
    float g = r0 * w[0] + r1 * w[1] + r2 * w[2] + r3 * w[3] + r4 * w[4] + r5 * w[5];
    atomicAdd(hp + j, g * xs[j]);
  }
}

// ---------------------------------------------------------------------------
// Phase 2: fused 4-layer MLP on nodes. 128-node tile lives in LDS across all
// layers; W staged per layer. Thread computes an 8x8 (nodes x dims) register
// tile; stride 132 (16B-aligned, breaks power-of-2 banks -> 2-way max = free).
// ---------------------------------------------------------------------------
#define LDA 132

__global__ __launch_bounds__(256, 1) void node_mlp(
    const float* __restrict__ h_in,
    const float* __restrict__ W1, const float* __restrict__ b1,
    const float* __restrict__ W2, const float* __restrict__ b2,
    const float* __restrict__ W3, const float* __restrict__ b3,
    const float* __restrict__ Wout, float* __restrict__ out) {
  __shared__ float sA[HID * LDA];  // 67.6 KB  (128-node tile)
  __shared__ float sW[HID * LDA];  // 67.6 KB  (current layer weights)

  int tid = threadIdx.x;
  int n0 = blockIdx.x * HID;

  // stage A tile (guard tail block; zero-fill invalid rows)
  for (int q = tid; q < HID * 32; q += 256) {
    int r = q >> 5, c = q & 31;
    float4 v = make_float4(0.f, 0.f, 0.f, 0.f);
    if (n0 + r < NN) v = ((const float4*)h_in)[(size_t)(n0 + r) * 32 + c];
    *(float4*)&sA[r * LDA + c * 4] = v;
  }

  const float* Ws[4] = {W1, W2, W3, Wout};
  const float* bs[3] = {b1, b2, b3};
  int tx = tid & 15, ty = tid >> 4;

  for (int layer = 0; layer < 4; ++layer) {
    // stage W for this layer (prev writeback to sA is fenced by the sync below)
    const float* Wl = Ws[layer];
    for (int q = tid; q < HID * 32; q += 256) {
      int r = q >> 5, c = q & 31;
      *(float4*)&sW[r * LDA + c * 4] = ((const float4*)Wl)[r * 32 + c];
    }
    __syncthreads();

    float acc[8][8];
#pragma unroll
    for (int l = 0; l < 8; ++l)
#pragma unroll
      for (int j = 0; j < 8; ++j) acc[l][j] = 0.f;

    for (int k = 0; k < HID; k += 4) {
      float4 af[8], wf[8];
#pragma unroll
      for (int l = 0; l < 8; ++l)
        af[l] = *(const float4*)&sA[(ty + 16 * l) * LDA + k];
#pragma unroll
      for (int j = 0; j < 8; ++j)
        wf[j] = *(const float4*)&sW[(tx + 16 * j) * LDA + k];
#pragma unroll
      for (int l = 0; l < 8; ++l)
#pragma unroll
        for (int j = 0; j < 8; ++j)
          acc[l][j] += af[l].x * wf[j].x + af[l].y * wf[j].y +
                       af[l].z * wf[j].z + af[l].w * wf[j].w;
    }
    __syncthreads();  // all reads of sA done before writeback

    if (layer < 3) {
      float bv[8];
#pragma unroll
      for (int j = 0; j < 8; ++j) bv[j] = bs[layer][tx + 16 * j];
#pragma unroll
      for (int l = 0; l < 8; ++l)
#pragma unroll
        for (int j = 0; j < 8; ++j) {
          float z = acc[l][j] + bv[j];
          sA[(ty + 16 * l) * LDA + tx + 16 * j] = z / (1.f + __expf(-z));
        }
    } else {
#pragma unroll
      for (int l = 0; l < 8; ++l) {
        int n = n0 + ty + 16 * l;
        if (n < NN) {
#pragma unroll
          for (int j = 0; j < 8; ++j)
            out[(size_t)n * HID + tx + 16 * j] = acc[l][j];
        }
      }
    }
  }
}

extern "C" void kernel_launch(void* const* d_in, const int* in_sizes, int n_in,
                              void* d_out, int out_size, void* d_ws, size_t ws_size,
                              hipStream_t stream) {
  const float* x     = (const float*)d_in[0];
  const float* rbf   = (const float*)d_in[1];
  const int*   idx   = (const int*)d_in[2];
  const float* W_rbf = (const float*)d_in[3];
  const float* W1 = (const float*)d_in[4];
  const float* b1 = (const float*)d_in[5];
  const float* W2 = (const float*)d_in[6];
  const float* b2 = (const float*)d_in[7];
  const float* W3 = (const float*)d_in[8];
  const float* b3 = (const float*)d_in[9];
  const float* Wout = (const float*)d_in[10];
  float* out = (float*)d_out;
  float* h = (float*)d_ws;  // N*H floats = 51.2 MB scratch

  hipMemsetAsync(h, 0, (size_t)NN * HID * sizeof(float), stream);

  int eblocks = (E_EDGES * 32 + 255) / 256;  // 200000 blocks
  edge_gate_scatter<<<eblocks, 256, 0, stream>>>(x, rbf, idx, W_rbf, h);

  int nblocks = (NN + HID - 1) / HID;  // 782 blocks
  node_mlp<<<nblocks, 256, 0, stream>>>(h, W1, b1, W2, b2, W3, b3, Wout, out);
}

// Round 2
// 1799.742 us; speedup vs baseline: 2.1879x; 2.1879x over previous
//
#include <hip/hip_runtime.h>
#include <hip/hip_bf16.h>

#define E_EDGES 1600000
#define NN 100000
#define HID 128
#define SCAN_B 391  // ceil(NN/256)

// ===========================================================================
// CSR build: counts -> exclusive scan -> permutation
// ===========================================================================
__global__ __launch_bounds__(256) void count_edges(const int* __restrict__ idx,
                                                   int* __restrict__ counts) {
  int e = blockIdx.x * 256 + threadIdx.x;
  if (e < E_EDGES) atomicAdd(&counts[idx[e]], 1);
}

__global__ __launch_bounds__(256) void scan_a(const int* __restrict__ counts,
                                              int* __restrict__ offsets,
                                              int* __restrict__ bsums) {
  __shared__ int s[256];
  int i = blockIdx.x * 256 + threadIdx.x;
  int v = (i < NN) ? counts[i] : 0;
  s[threadIdx.x] = v;
  __syncthreads();
  for (int d = 1; d < 256; d <<= 1) {
    int t = (threadIdx.x >= d) ? s[threadIdx.x - d] : 0;
    __syncthreads();
    s[threadIdx.x] += t;
    __syncthreads();
  }
  if (i < NN) offsets[i + 1] = s[threadIdx.x];  // inclusive within block
  if (threadIdx.x == 255) bsums[blockIdx.x] = s[255];
}

__global__ __launch_bounds__(512) void scan_b(int* __restrict__ bsums) {
  __shared__ int s[512];
  int t = threadIdx.x;
  int v = (t < SCAN_B) ? bsums[t] : 0;
  s[t] = v;
  __syncthreads();
  for (int d = 1; d < 512; d <<= 1) {
    int u = (t >= d) ? s[t - d] : 0;
    __syncthreads();
    s[t] += u;
    __syncthreads();
  }
  if (t < SCAN_B) bsums[t] = s[t] - v;  // exclusive block offsets
}

__global__ __launch_bounds__(256) void scan_c(int* __restrict__ offsets,
                                              const int* __restrict__ bsums) {
  int i = blockIdx.x * 256 + threadIdx.x;
  if (i < NN) offsets[i + 1] += bsums[blockIdx.x];
  if (i == 0) offsets[0] = 0;
}

__global__ __launch_bounds__(256) void cursor_init(const int* __restrict__ offsets,
                                                   int* __restrict__ cursor) {
  int i = blockIdx.x * 256 + threadIdx.x;
  if (i < NN) cursor[i] = offsets[i];
}

__global__ __launch_bounds__(256) void scatter_perm(const int* __restrict__ idx,
                                                    int* __restrict__ cursor,
                                                    int* __restrict__ perm) {
  int e = blockIdx.x * 256 + threadIdx.x;
  if (e < E_EDGES) {
    int n = idx[e];
    int p = atomicAdd(&cursor[n], 1);
    perm[p] = e;
  }
}

// ===========================================================================
// Gather: one wave per node; lane owns dims {2l, 2l+1}. x row read coalesced
// (64 lanes x float2 = 512B), h written exactly once (no atomics, no memset).
// ===========================================================================
__global__ __launch_bounds__(256) void gather_nodes(
    const float* __restrict__ x, const float* __restrict__ rbf,
    const float* __restrict__ W_rbf, const int* __restrict__ offsets,
    const int* __restrict__ perm, float* __restrict__ h) {
  int wave = (int)((blockIdx.x * 256 + threadIdx.x) >> 6);
  int lane = threadIdx.x & 63;
  if (wave >= NN) return;
  int n = wave;
  int start = offsets[n], end = offsets[n + 1];

  float w0[6], w1[6];
#pragma unroll
  for (int k = 0; k < 6; ++k) {
    w0[k] = W_rbf[(2 * lane) * 6 + k];
    w1[k] = W_rbf[(2 * lane + 1) * 6 + k];
  }
  float a0 = 0.f, a1 = 0.f;
  for (int j = start; j < end; ++j) {
    int e = __builtin_amdgcn_readfirstlane(perm[j]);  // wave-uniform -> s_load path
    const float* rb = rbf + (size_t)e * 6;
    float r0 = rb[0], r1 = rb[1], r2 = rb[2], r3 = rb[3], r4 = rb[4], r5 = rb[5];
    float2 xv = *(const float2*)(x + (size_t)e * HID + 2 * lane);
    float g0 = r0 * w0[0] + r1 * w0[1] + r2 * w0[2] + r3 * w0[3] + r4 * w0[4] + r5 * w0[5];
    float g1 = r0 * w1[0] + r1 * w1[1] + r2 * w1[2] + r3 * w1[3] + r4 * w1[4] + r5 * w1[5];
    a0 += g0 * xv.x;
    a1 += g1 * xv.y;
  }
  *(float2*)(h + (size_t)n * HID + 2 * lane) = make_float2(a0, a1);
}

// ===========================================================================
// Fallback (R1 path) if ws_size is too small for CSR scratch
// ===========================================================================
__global__ __launch_bounds__(256) void edge_gate_scatter(
    const float* __restrict__ x, const float* __restrict__ rbf,
    const int* __restrict__ idx, const float* __restrict__ W_rbf,
    float* __restrict__ h) {
  __shared__ float sW[HID * 6];
  for (int t = threadIdx.x; t < HID * 6; t += 256) sW[t] = W_rbf[t];
  __syncthreads();
  long long gid = (long long)blockIdx.x * 256 + threadIdx.x;
  long long e = gid >> 5;
  int c = (int)(gid & 31);
  if (e >= E_EDGES) return;
  const float* rb = rbf + e * 6;
  float r0 = rb[0], r1 = rb[1], r2 = rb[2], r3 = rb[3], r4 = rb[4], r5 = rb[5];
  float4 xv = ((const float4*)x)[e * 32 + c];
  int node = idx[e];
  float* hp = h + (long long)node * HID + c * 4;
  float xs[4] = {xv.x, xv.y, xv.z, xv.w};
#pragma unroll
  for (int j = 0; j < 4; ++j) {
    const float* w = &sW[(c * 4 + j) * 6];
    float g = r0 * w[0] + r1 * w[1] + r2 * w[2] + r3 * w[3] + r4 * w[4] + r5 * w[5];
    atomicAdd(hp + j, g * xs[j]);
  }
}

// ===========================================================================
// Phase 2: fused 4-layer MLP (unchanged from R1 — known correct)
// ===========================================================================
#define LDA 132

__global__ __launch_bounds__(256, 1) void node_mlp(
    const float* __restrict__ h_in,
    const float* __restrict__ W1, const float* __restrict__ b1,
    const float* __restrict__ W2, const float* __restrict__ b2,
    const float* __restrict__ W3, const float* __restrict__ b3,
    const float* __restrict__ Wout, float* __restrict__ out) {
  __shared__ float sA[HID * LDA];
  __shared__ float sW[HID * LDA];

  int tid = threadIdx.x;
  int n0 = blockIdx.x * HID;

  for (int q = tid; q < HID * 32; q += 256) {
    int r = q >> 5, c = q & 31;
    float4 v = make_float4(0.f, 0.f, 0.f, 0.f);
    if (n0 + r < NN) v = ((const float4*)h_in)[(size_t)(n0 + r) * 32 + c];
    *(float4*)&sA[r * LDA + c * 4] = v;
  }

  const float* Ws[4] = {W1, W2, W3, Wout};
  const float* bs[3] = {b1, b2, b3};
  int tx = tid & 15, ty = tid >> 4;

  for (int layer = 0; layer < 4; ++layer) {
    const float* Wl = Ws[layer];
    for (int q = tid; q < HID * 32; q += 256) {
      int r = q >> 5, c = q & 31;
      *(float4*)&sW[r * LDA + c * 4] = ((const float4*)Wl)[r * 32 + c];
    }
    __syncthreads();

    float acc[8][8];
#pragma unroll
    for (int l = 0; l < 8; ++l)
#pragma unroll
      for (int j = 0; j < 8; ++j) acc[l][j] = 0.f;

    for (int k = 0; k < HID; k += 4) {
      float4 af[8], wf[8];
#pragma unroll
      for (int l = 0; l < 8; ++l)
        af[l] = *(const float4*)&sA[(ty + 16 * l) * LDA + k];
#pragma unroll
      for (int j = 0; j < 8; ++j)
        wf[j] = *(const float4*)&sW[(tx + 16 * j) * LDA + k];
#pragma unroll
      for (int l = 0; l < 8; ++l)
#pragma unroll
        for (int j = 0; j < 8; ++j)
          acc[l][j] += af[l].x * wf[j].x + af[l].y * wf[j].y +
                       af[l].z * wf[j].z + af[l].w * wf[j].w;
    }
    __syncthreads();

    if (layer < 3) {
      float bv[8];
#pragma unroll
      for (int j = 0; j < 8; ++j) bv[j] = bs[layer][tx + 16 * j];
#pragma unroll
      for (int l = 0; l < 8; ++l)
#pragma unroll
        for (int j = 0; j < 8; ++j) {
          float z = acc[l][j] + bv[j];
          sA[(ty + 16 * l) * LDA + tx + 16 * j] = z / (1.f + __expf(-z));
        }
    } else {
#pragma unroll
      for (int l = 0; l < 8; ++l) {
        int n = n0 + ty + 16 * l;
        if (n < NN) {
#pragma unroll
          for (int j = 0; j < 8; ++j)
            out[(size_t)n * HID + tx + 16 * j] = acc[l][j];
        }
      }
    }
  }
}

extern "C" void kernel_launch(void* const* d_in, const int* in_sizes, int n_in,
                              void* d_out, int out_size, void* d_ws, size_t ws_size,
                              hipStream_t stream) {
  const float* x     = (const float*)d_in[0];
  const float* rbf   = (const float*)d_in[1];
  const int*   idx   = (const int*)d_in[2];
  const float* W_rbf = (const float*)d_in[3];
  const float* W1 = (const float*)d_in[4];
  const float* b1 = (const float*)d_in[5];
  const float* W2 = (const float*)d_in[6];
  const float* b2 = (const float*)d_in[7];
  const float* W3 = (const float*)d_in[8];
  const float* b3 = (const float*)d_in[9];
  const float* Wout = (const float*)d_in[10];
  float* out = (float*)d_out;

  // ws layout
  char* wp = (char*)d_ws;
  float* h = (float*)wp;                 wp += (size_t)NN * HID * sizeof(float);
  int* counts  = (int*)wp;               wp += (size_t)NN * sizeof(int);
  int* offsets = (int*)wp;               wp += (size_t)(NN + 1) * sizeof(int);
  int* cursor  = (int*)wp;               wp += (size_t)NN * sizeof(int);
  int* perm    = (int*)wp;               wp += (size_t)E_EDGES * sizeof(int);
  int* bsums   = (int*)wp;               wp += 512 * sizeof(int);
  size_t needed = (size_t)(wp - (char*)d_ws);

  int eblk = (E_EDGES + 255) / 256;   // 6250
  int nblk = (NN + 255) / 256;        // 391

  if (ws_size >= needed) {
    hipMemsetAsync(counts, 0, (size_t)NN * sizeof(int), stream);
    count_edges<<<eblk, 256, 0, stream>>>(idx, counts);
    scan_a<<<SCAN_B, 256, 0, stream>>>(counts, offsets, bsums);
    scan_b<<<1, 512, 0, stream>>>(bsums);
    scan_c<<<nblk, 256, 0, stream>>>(offsets, bsums);
    cursor_init<<<nblk, 256, 0, stream>>>(offsets, cursor);
    scatter_perm<<<eblk, 256, 0, stream>>>(idx, cursor, perm);
    int gblk = (NN * 64 + 255) / 256;  // 25000 blocks, 1 wave/node
    gather_nodes<<<gblk, 256, 0, stream>>>(x, rbf, W_rbf, offsets, perm, h);
  } else {
    // fallback: atomic scatter (R1 path)
    hipMemsetAsync(h, 0, (size_t)NN * HID * sizeof(float), stream);
    int eblocks = (E_EDGES * 32 + 255) / 256;
    edge_gate_scatter<<<eblocks, 256, 0, stream>>>(x, rbf, idx, W_rbf, h);
  }

  int mblocks = (NN + HID - 1) / HID;  // 782
  node_mlp<<<mblocks, 256, 0, stream>>>(h, W1, b1, W2, b2, W3, b3, Wout, out);
}